// Round 8
// baseline (100.163 us; speedup 1.0000x reference)
//
#include <hip/hip_runtime.h>
#include <math.h>

// Problem constants (fixed by setup_inputs)
constexpr int N = 8192;   // rows
constexpr int D = 512;    // feature dim
constexpr int C = 64;     // classes
constexpr int CAP_PC = 512;   // per-class list cap (counts ~128 +/- 11)
constexpr int CAP_W = 256;    // per-wave staging cap (scan segment = 2048 rows)
constexpr double TOTAL_PAIRS = 33550336.0;  // N*(N-1)/2

// k_main grid: [0, NB_SUM) classsum blocks, [NB_SUM, NB_MAIN) cross blocks
constexpr int NB_SUM = C * 2;     // (class c, colgroup g in {0,1}) -> 256 cols each
constexpr int NB_CROSS = 128;
constexpr int NB_MAIN = NB_SUM + NB_CROSS;
constexpr int NCP = NB_CROSS * 4; // cross partial slots (one per wave)

// ws layout (32-bit elements) — everything written exactly once per call:
//   [0, 32768)        S[c][d]       (write-once by k_main sum blocks)
//   [32768, 33280)    cross_part[NCP] (write-once by k_main cross waves)
//   [33280, 33344)    Q[c]
//   [33344, 33408)    cnt[c]
//   [33408, 41600)    lbl[N]
//   [41600, 49792)    sq[N]

// ------- kernel 1: per-row argmax + sum-of-squares (pure streaming) -------
// one wave per row; grid = N/4 = 2048 blocks of 256
__global__ __launch_bounds__(256) void k_rows(const float* __restrict__ X,
                                              const float* __restrict__ L,
                                              int* __restrict__ lbl,
                                              float* __restrict__ sq) {
    int wv = threadIdx.x >> 6, lane = threadIdx.x & 63;
    int row = blockIdx.x * 4 + wv;  // grid covers N exactly

    // argmax over 64 label logits: lane l holds class l (first-max tie rule)
    float v = L[(size_t)row * C + lane];
    int idx = lane;
#pragma unroll
    for (int off = 1; off < 64; off <<= 1) {
        float ov = __shfl_xor(v, off);
        int oi = __shfl_xor(idx, off);
        if (ov > v || (ov == v && oi < idx)) { v = ov; idx = oi; }
    }

    // sum of squares: lane reads 8 contiguous floats (2x float4)
    const float4* Xr = (const float4*)(X + (size_t)row * D);
    float4 a = Xr[lane * 2], b = Xr[lane * 2 + 1];
    float s = a.x * a.x + a.y * a.y + a.z * a.z + a.w * a.w
            + b.x * b.x + b.y * b.y + b.z * b.z + b.w * b.w;
#pragma unroll
    for (int off = 1; off < 64; off <<= 1) s += __shfl_xor(s, off);

    if (lane == 0) { lbl[row] = idx; sq[row] = s; }
}

// ------- kernel 2 (fused): class column-sums + cross hinge, all write-once ----
// Every block rebuilds the row list(s) it needs from the L2-hot lbl[] (32 KB)
// via per-wave ballot compaction — no global cls_list, no atomics, no zeroing.
__global__ __launch_bounds__(256) void k_main(const float* __restrict__ X,
                                              const int* __restrict__ lbl,
                                              const float* __restrict__ sq,
                                              float* __restrict__ S,
                                              float* __restrict__ cross_part,
                                              float* __restrict__ Q,
                                              unsigned* __restrict__ cnt) {
    __shared__ int stageA[4][CAP_W];
    __shared__ int stageB[4][CAP_W];
    __shared__ int listA[CAP_PC];
    __shared__ int listB[CAP_PC];
    __shared__ unsigned wcntA[4], wcntB[4];
    __shared__ float qred[256];
    __shared__ unsigned long long blkmask;

    int wv = threadIdx.x >> 6, lane = threadIdx.x & 63;
    int b = blockIdx.x;

    if (b < NB_SUM) {
        // ================= classsum: block (c, g) =================
        int c = b >> 1;
        int g = b & 1;

        // build class-c row list: wave w scans rows [w*2048, (w+1)*2048)
        unsigned my = 0;
        float qs = 0.f;
        int base = wv * (N / 4);
        for (int it = 0; it < (N / 4) / 64; it++) {
            int r = base + it * 64 + lane;
            bool m = (lbl[r] == c);
            unsigned long long mask = __ballot(m);
            if (m) {
                unsigned pos = my + (unsigned)__popcll(mask & ((1ull << lane) - 1ull));
                if (pos < CAP_W) stageA[wv][pos] = r;
                if (g == 0) qs += sq[r];
            }
            my += (unsigned)__popcll(mask);
        }
        if (lane == 0) wcntA[wv] = my;
        __syncthreads();
        unsigned pre = 0, tot = 0;
        for (int w = 0; w < 4; w++) { if (w < wv) pre += wcntA[w]; tot += wcntA[w]; }
        unsigned nw_ = min(my, (unsigned)CAP_W);
        for (unsigned k = lane; k < nw_; k += 64) {
            unsigned dst = pre + k;
            if (dst < (unsigned)CAP_PC) listA[dst] = stageA[wv][k];
        }
        __syncthreads();
        int n = (int)min(tot, (unsigned)CAP_PC);

        // column sums: 256 threads = 256 cols, write-once into S
        int col = g * 256 + threadIdx.x;
        float acc[8] = {0, 0, 0, 0, 0, 0, 0, 0};
        int k = 0;
        for (; k + 8 <= n; k += 8) {
#pragma unroll
            for (int u = 0; u < 8; u++)
                acc[u] += X[(size_t)listA[k + u] * D + col];
        }
        for (; k < n; k++) acc[0] += X[(size_t)listA[k] * D + col];
        S[(size_t)c * D + col] = ((acc[0] + acc[1]) + (acc[2] + acc[3]))
                               + ((acc[4] + acc[5]) + (acc[6] + acc[7]));

        if (g == 0) {  // also write Q[c], cnt[c]
#pragma unroll
            for (int off = 1; off < 64; off <<= 1) qs += __shfl_xor(qs, off);
            if (lane == 0) qred[wv] = qs;
            __syncthreads();
            if (threadIdx.x == 0) {
                Q[c] = (qred[0] + qred[1]) + (qred[2] + qred[3]);
                cnt[c] = (unsigned)n;
            }
        }
    } else {
        // ================= cross hinge =================
        // m1/m2 from per-block class-presence mask (deterministic)
        unsigned long long seen = 0;
        for (int r = threadIdx.x; r < N; r += 256)
            seen |= (1ull << lbl[r]);
#pragma unroll
        for (int off = 1; off < 64; off <<= 1) seen |= __shfl_xor(seen, off);
        if (threadIdx.x == 0) blkmask = seen;
        __syncthreads();
        unsigned long long mask = blkmask;
        int m1 = 63 - __clzll(mask | 1ull);
        unsigned long long mask2 = mask & ~(1ull << m1);
        int m2 = mask2 ? (63 - __clzll(mask2)) : -1;

        int na = 0, nb = 0;
        if (m2 >= 0) {
            // build A (lbl==m2) and B (lbl==m1) lists via ballot compaction
            unsigned myA = 0, myB = 0;
            int base = wv * (N / 4);
            for (int it = 0; it < (N / 4) / 64; it++) {
                int r = base + it * 64 + lane;
                int l = lbl[r];
                unsigned long long mA = __ballot(l == m2);
                unsigned long long mB = __ballot(l == m1);
                unsigned long long below = (1ull << lane) - 1ull;
                if (l == m2) {
                    unsigned pos = myA + (unsigned)__popcll(mA & below);
                    if (pos < CAP_W) stageA[wv][pos] = r;
                }
                if (l == m1) {
                    unsigned pos = myB + (unsigned)__popcll(mB & below);
                    if (pos < CAP_W) stageB[wv][pos] = r;
                }
                myA += (unsigned)__popcll(mA);
                myB += (unsigned)__popcll(mB);
            }
            if (lane == 0) { wcntA[wv] = myA; wcntB[wv] = myB; }
            __syncthreads();
            unsigned preA = 0, totA = 0, preB = 0, totB = 0;
            for (int w = 0; w < 4; w++) {
                if (w < wv) { preA += wcntA[w]; preB += wcntB[w]; }
                totA += wcntA[w]; totB += wcntB[w];
            }
            unsigned nA_ = min(myA, (unsigned)CAP_W);
            for (unsigned k = lane; k < nA_; k += 64) {
                unsigned dst = preA + k;
                if (dst < (unsigned)CAP_PC) listA[dst] = stageA[wv][k];
            }
            unsigned nB_ = min(myB, (unsigned)CAP_W);
            for (unsigned k = lane; k < nB_; k += 64) {
                unsigned dst = preB + k;
                if (dst < (unsigned)CAP_PC) listB[dst] = stageB[wv][k];
            }
            __syncthreads();
            na = (int)min(totA, (unsigned)CAP_PC);
            nb = (int)min(totB, (unsigned)CAP_PC);
        }

        // pair loop: grid-stride over (i, chunk-of-8-j); hs=0 if no pairs
        float hs = 0.f;
        if (na > 0 && nb > 0) {
            int gw = (b - NB_SUM) * 4 + wv, nw = NB_CROSS * 4;
            int nbc = (nb + 7) >> 3;
            int nchunk = na * nbc;
            for (int ch = gw; ch < nchunk; ch += nw) {
                int ai = ch / nbc;
                int bc = ch - ai * nbc;
                int i = listA[ai];
                const float4* Xi = (const float4*)(X + (size_t)i * D);
                float4 ia = Xi[lane * 2], ib = Xi[lane * 2 + 1];
                float sqi = sq[i];
                int b0 = bc * 8;
#pragma unroll
                for (int u = 0; u < 8; u++) {
                    int bi = b0 + u;
                    int j = listB[bi < nb ? bi : 0];
                    const float4* Xj = (const float4*)(X + (size_t)j * D);
                    float4 ja = Xj[lane * 2], jb = Xj[lane * 2 + 1];
                    float d = ia.x * ja.x + ia.y * ja.y + ia.z * ja.z + ia.w * ja.w
                            + ib.x * jb.x + ib.y * jb.y + ib.z * jb.z + ib.w * jb.w;
#pragma unroll
                    for (int off = 1; off < 64; off <<= 1) d += __shfl_xor(d, off);
                    float d2 = fmaxf(sqi + sq[j] - 2.f * d, 0.f);
                    float h = fmaxf(1.f - sqrtf(d2), 0.f);
                    if (bi < nb) hs += h * h;
                }
            }
        }
        // unconditional write-once partial (one slot per wave)
        if (lane == 0) cross_part[(b - NB_SUM) * 4 + wv] = hs;
    }
}

// ---------------- kernel 3: final combine (double precision) ----------------
__global__ __launch_bounds__(256) void k_final(const float* __restrict__ S,
                                               const float* __restrict__ cross_part,
                                               const float* __restrict__ Q,
                                               const unsigned* __restrict__ cnt,
                                               float* __restrict__ out) {
    __shared__ double r2[256], r1[256], rc[256];
    const float4* S4 = (const float4*)S;
    double t2 = 0.0;
    for (int i = threadIdx.x; i < C * D / 4; i += 256) {
        float4 s = S4[i];
        t2 += (double)s.x * s.x + (double)s.y * s.y
            + (double)s.z * s.z + (double)s.w * s.w;
    }
    double t1 = 0.0, pc = 0.0;
    if (threadIdx.x < C) {
        double nc = (double)cnt[threadIdx.x];
        t1 = nc * (double)Q[threadIdx.x];
        pc = nc * (nc - 1.0) * 0.5;
    }
    double cs = 0.0;
    for (int i = threadIdx.x; i < NCP; i += 256) cs += (double)cross_part[i];
    r2[threadIdx.x] = t2;
    r1[threadIdx.x] = t1 + cs * 1e-30;  // keep slots separate: fold cs below
    rc[threadIdx.x] = pc;
    // reuse r1 for t1 and pack cs into a second pass to avoid a 4th array:
    __syncthreads();
    // tree-reduce t2 / t1 / pc
    for (int s = 128; s > 0; s >>= 1) {
        if (threadIdx.x < s) {
            r2[threadIdx.x] += r2[threadIdx.x + s];
            rc[threadIdx.x] += rc[threadIdx.x + s];
        }
        __syncthreads();
    }
    // separate reductions for t1 and cs (reuse r1 buffer twice)
    __syncthreads();
    r1[threadIdx.x] = t1;
    __syncthreads();
    for (int s = 128; s > 0; s >>= 1) {
        if (threadIdx.x < s) r1[threadIdx.x] += r1[threadIdx.x + s];
        __syncthreads();
    }
    double t1sum = r1[0];
    __syncthreads();
    r1[threadIdx.x] = cs;
    __syncthreads();
    for (int s = 128; s > 0; s >>= 1) {
        if (threadIdx.x < s) r1[threadIdx.x] += r1[threadIdx.x + s];
        __syncthreads();
    }
    if (threadIdx.x == 0) {
        double same = (rc[0] > 0.0) ? (t1sum - r2[0]) / rc[0] : 0.0;
        double diff = r1[0] / TOTAL_PAIRS;
        out[0] = (float)(same + diff);
    }
}

extern "C" void kernel_launch(void* const* d_in, const int* in_sizes, int n_in,
                              void* d_out, int out_size, void* d_ws, size_t ws_size,
                              hipStream_t stream) {
    const float* X = (const float*)d_in[0];   // outputs [N, D] fp32
    const float* L = (const float*)d_in[1];   // labels  [N, C] fp32
    float* ws = (float*)d_ws;

    float* S = ws;                               // [0, 32768)
    float* cross_part = ws + 32768;              // [32768, 33280)
    float* Q = ws + 33280;                       // 64
    unsigned* cnt = (unsigned*)(ws + 33344);     // 64
    int* lbl = (int*)(ws + 33408);               // N
    float* sq = ws + 41600;                      // N
    float* out = (float*)d_out;

    hipLaunchKernelGGL(k_rows, dim3(N / 4), dim3(256), 0, stream, X, L, lbl, sq);
    hipLaunchKernelGGL(k_main, dim3(NB_MAIN), dim3(256), 0, stream,
                       X, lbl, sq, S, cross_part, Q, cnt);
    hipLaunchKernelGGL(k_final, dim3(1), dim3(256), 0, stream,
                       S, cross_part, Q, cnt, out);
}

// Round 9
// 99.328 us; speedup vs baseline: 1.0084x; 1.0084x over previous
//
#include <hip/hip_runtime.h>
#include <math.h>

// Problem constants (fixed by setup_inputs)
constexpr int N = 8192;   // rows
constexpr int D = 512;    // feature dim
constexpr int C = 64;     // classes
constexpr int CAP_W = 256;    // per-wave staging cap (2048-row segment, exp ~32)
constexpr int CAP_PC = 512;   // per-class list cap (counts ~128 +/- 11)
constexpr double TOTAL_PAIRS = 33550336.0;  // N*(N-1)/2

// kernel-2 grid: sum blocks then cross blocks
constexpr int NB_SUMK = 256;    // (class c = b>>2) x (colgroup g = b&3), 128 cols
constexpr int NB_CROSSK = 128;  // cross blocks, 4 wave-partials each
constexpr int NB_K2 = NB_SUMK + NB_CROSSK;   // 384

// ws layout:
//   doubles [0,896):  s2_part[0,256) | nq_part[256,320) | pc_part[320,384)
//                     | cross_part[384,896)        (all write-once per call)
//   floats from 1792: done @1792 (zeroed by k_rows) | lbl @[1796,9988)
//                     | sq @[9988,18180)

// ------- kernel 1: per-row argmax + sum-of-squares + zero done -------
// one wave per row; grid = N/4 = 2048 blocks of 256
__global__ __launch_bounds__(256) void k_rows(const float* __restrict__ X,
                                              const float* __restrict__ L,
                                              int* __restrict__ lbl,
                                              float* __restrict__ sq,
                                              unsigned* __restrict__ done) {
    if (blockIdx.x == 0 && threadIdx.x == 0) *done = 0;  // the ONLY word needing init

    int wv = threadIdx.x >> 6, lane = threadIdx.x & 63;
    int row = blockIdx.x * 4 + wv;  // covers [0, 8192) exactly

    // argmax over 64 label logits: lane l holds class l (first-max tie rule)
    float v = L[(size_t)row * C + lane];
    int idx = lane;
#pragma unroll
    for (int off = 1; off < 64; off <<= 1) {
        float ov = __shfl_xor(v, off);
        int oi = __shfl_xor(idx, off);
        if (ov > v || (ov == v && oi < idx)) { v = ov; idx = oi; }
    }

    // sum of squares: lane reads 8 contiguous floats (2x float4)
    const float4* Xr = (const float4*)(X + (size_t)row * D);
    float4 a = Xr[lane * 2], b = Xr[lane * 2 + 1];
    float s = a.x * a.x + a.y * a.y + a.z * a.z + a.w * a.w
            + b.x * b.x + b.y * b.y + b.z * b.z + b.w * b.w;
#pragma unroll
    for (int off = 1; off < 64; off <<= 1) s += __shfl_xor(s, off);

    if (lane == 0) { lbl[row] = idx; sq[row] = s; }
}

// ------- kernel 2: everything else, all write-once + last-block combine -------
// blocks [0,256): class column sums -> local square-reduce -> 1 double partial
// blocks [256,384): cross hinge -> 4 double wave-partials
// last block (fence+done protocol, R5-proven): final combine -> out[0]
__global__ __launch_bounds__(256) void k2(const float* __restrict__ X,
                                          const int* __restrict__ lbl,
                                          const float* __restrict__ sq,
                                          double* __restrict__ dpart,
                                          unsigned* __restrict__ done,
                                          float* __restrict__ out) {
    double* s2_part = dpart;            // [0,256)
    double* nq_part = dpart + 256;      // [256,320)
    double* pc_part = dpart + 320;      // [320,384)
    double* cr_part = dpart + 384;      // [384,896)

    __shared__ int stageA[4][CAP_W];
    __shared__ int stageB[4][CAP_W];
    __shared__ int listA[CAP_PC];
    __shared__ int listB[CAP_PC];
    __shared__ unsigned wcntA[4], wcntB[4];
    __shared__ float wq[4];
    __shared__ unsigned long long wmask[4];
    __shared__ float cs0[128];
    __shared__ double red1[256], red2[256], red3[256];
    __shared__ bool last;

    int wv = threadIdx.x >> 6, lane = threadIdx.x & 63;
    int b = blockIdx.x;

    if (b < NB_SUMK) {
        // ============ sum block: class c, colgroup g (128 cols) ============
        int c = b >> 2;
        int g = b & 3;

        // build class-c row list: wave w scans rows [w*2048,(w+1)*2048)
        unsigned my = 0;
        float qs = 0.f;
        int base = wv * (N / 4);
        for (int it = 0; it < (N / 4) / 64; it++) {
            int r = base + it * 64 + lane;
            bool m = (lbl[r] == c);
            unsigned long long mask = __ballot(m);
            if (m) {
                unsigned pos = my + (unsigned)__popcll(mask & ((1ull << lane) - 1ull));
                if (pos < CAP_W) stageA[wv][pos] = r;
                if (g == 0) qs += sq[r];
            }
            my += (unsigned)__popcll(mask);
        }
        if (lane == 0) wcntA[wv] = my;
        if (g == 0) {
#pragma unroll
            for (int off = 1; off < 64; off <<= 1) qs += __shfl_xor(qs, off);
            if (lane == 0) wq[wv] = qs;
        }
        __syncthreads();
        unsigned pre = 0, tot = 0;
        for (int w = 0; w < 4; w++) { if (w < wv) pre += wcntA[w]; tot += wcntA[w]; }
        unsigned nw_ = min(my, (unsigned)CAP_W);
        for (unsigned k = lane; k < nw_; k += 64) {
            unsigned dst = pre + k;
            if (dst < (unsigned)CAP_PC) listA[dst] = stageA[wv][k];
        }
        __syncthreads();
        int n = (int)min(tot, (unsigned)CAP_PC);

        // column sums: thread = (rowsplit rs, local col); combine splits in LDS
        int colLocal = threadIdx.x & 127;
        int rs = threadIdx.x >> 7;              // 0 or 1
        int col = g * 128 + colLocal;
        float acc[8] = {0, 0, 0, 0, 0, 0, 0, 0};
        int k = rs;
        for (; k + 14 < n; k += 16) {           // 8 rows per split per batch
#pragma unroll
            for (int u = 0; u < 8; u++)
                acc[u] += X[(size_t)listA[k + 2 * u] * D + col];
        }
        for (; k < n; k += 2) acc[0] += X[(size_t)listA[k] * D + col];
        float t = ((acc[0] + acc[1]) + (acc[2] + acc[3]))
                + ((acc[4] + acc[5]) + (acc[6] + acc[7]));
        if (rs == 0) cs0[colLocal] = t;
        __syncthreads();
        double s2 = 0.0;
        if (rs == 1) {
            float totc = cs0[colLocal] + t;     // complete column sum S[c][col]
            s2 = (double)totc * (double)totc;
        }
        // block-reduce s2 -> one partial
        red1[threadIdx.x] = s2;
        __syncthreads();
        for (int s = 128; s > 0; s >>= 1) {
            if (threadIdx.x < s) red1[threadIdx.x] += red1[threadIdx.x + s];
            __syncthreads();
        }
        if (threadIdx.x == 0) {
            s2_part[b] = red1[0];
            if (g == 0) {
                double nc = (double)n;
                nq_part[c] = nc * (double)((wq[0] + wq[1]) + (wq[2] + wq[3]));
                pc_part[c] = nc * (nc - 1.0) * 0.5;
            }
        }
    } else {
        // ============ cross block: hinge over (class m2) x (class m1) ============
        // presence mask: per-wave OR then cross-wave OR (R8 only used wave 0 - fixed)
        unsigned long long seen = 0;
        for (int r = threadIdx.x; r < N; r += 256) seen |= (1ull << lbl[r]);
#pragma unroll
        for (int off = 1; off < 64; off <<= 1) seen |= __shfl_xor(seen, off);
        if (lane == 0) wmask[wv] = seen;
        __syncthreads();
        unsigned long long mask = (wmask[0] | wmask[1]) | (wmask[2] | wmask[3]);
        int m1 = 63 - __clzll(mask | 1ull);
        unsigned long long mask2 = mask & ~(1ull << m1);
        int m2 = mask2 ? (63 - __clzll(mask2)) : -1;

        int na = 0, nb = 0;
        if (m2 >= 0) {
            unsigned myA = 0, myB = 0;
            int base = wv * (N / 4);
            for (int it = 0; it < (N / 4) / 64; it++) {
                int r = base + it * 64 + lane;
                int l = lbl[r];
                unsigned long long mA = __ballot(l == m2);
                unsigned long long mB = __ballot(l == m1);
                unsigned long long below = (1ull << lane) - 1ull;
                if (l == m2) {
                    unsigned pos = myA + (unsigned)__popcll(mA & below);
                    if (pos < CAP_W) stageA[wv][pos] = r;
                }
                if (l == m1) {
                    unsigned pos = myB + (unsigned)__popcll(mB & below);
                    if (pos < CAP_W) stageB[wv][pos] = r;
                }
                myA += (unsigned)__popcll(mA);
                myB += (unsigned)__popcll(mB);
            }
            if (lane == 0) { wcntA[wv] = myA; wcntB[wv] = myB; }
            __syncthreads();
            unsigned preA = 0, totA = 0, preB = 0, totB = 0;
            for (int w = 0; w < 4; w++) {
                if (w < wv) { preA += wcntA[w]; preB += wcntB[w]; }
                totA += wcntA[w]; totB += wcntB[w];
            }
            unsigned nA_ = min(myA, (unsigned)CAP_W);
            for (unsigned k = lane; k < nA_; k += 64) {
                unsigned dst = preA + k;
                if (dst < (unsigned)CAP_PC) listA[dst] = stageA[wv][k];
            }
            unsigned nB_ = min(myB, (unsigned)CAP_W);
            for (unsigned k = lane; k < nB_; k += 64) {
                unsigned dst = preB + k;
                if (dst < (unsigned)CAP_PC) listB[dst] = stageB[wv][k];
            }
            __syncthreads();
            na = (int)min(totA, (unsigned)CAP_PC);
            nb = (int)min(totB, (unsigned)CAP_PC);
        }

        float hs = 0.f;
        if (na > 0 && nb > 0) {
            int bc = b - NB_SUMK;
            int gw = bc * 4 + wv, nw = NB_CROSSK * 4;
            int nbc = (nb + 7) >> 3;
            int nchunk = na * nbc;
            for (int ch = gw; ch < nchunk; ch += nw) {
                int ai = ch / nbc;
                int bcix = ch - ai * nbc;
                int i = listA[ai];
                const float4* Xi = (const float4*)(X + (size_t)i * D);
                float4 ia = Xi[lane * 2], ib = Xi[lane * 2 + 1];
                float sqi = sq[i];
                int b0 = bcix * 8;
#pragma unroll
                for (int u = 0; u < 8; u++) {
                    int bi = b0 + u;
                    int j = listB[bi < nb ? bi : 0];
                    const float4* Xj = (const float4*)(X + (size_t)j * D);
                    float4 ja = Xj[lane * 2], jb = Xj[lane * 2 + 1];
                    float d = ia.x * ja.x + ia.y * ja.y + ia.z * ja.z + ia.w * ja.w
                            + ib.x * jb.x + ib.y * jb.y + ib.z * jb.z + ib.w * jb.w;
#pragma unroll
                    for (int off = 1; off < 64; off <<= 1) d += __shfl_xor(d, off);
                    float d2 = fmaxf(sqi + sq[j] - 2.f * d, 0.f);
                    float h = fmaxf(1.f - sqrtf(d2), 0.f);
                    if (bi < nb) hs += h * h;
                }
            }
        }
        // unconditional write-once wave partial (all lanes hold identical hs)
        if (lane == 0) cr_part[(b - NB_SUMK) * 4 + wv] = (double)hs;
    }

    // ---- completion protocol (R5-proven pattern; pre-fence writes are 1-4 scalars) ----
    __syncthreads();
    if (threadIdx.x == 0) {
        __threadfence();                    // release partial writes device-wide
        unsigned prev = atomicAdd(done, 1u);
        last = (prev == (unsigned)(NB_K2 - 1));
    }
    __syncthreads();
    if (!last) return;
    __threadfence();                        // acquire

    // ---- final combine: 896 double partials -> out[0] ----
    volatile const double* vp = (volatile const double*)dpart;
    double a1 = -vp[threadIdx.x];           // -s2_part (exactly 256 slots)
    double a2 = 0.0, a3 = 0.0;
    if (threadIdx.x < C) {
        a1 += vp[256 + threadIdx.x];        // +nq_part
        a2 = vp[320 + threadIdx.x];         // pair counts
    }
    for (int i = threadIdx.x; i < NB_CROSSK * 4; i += 256)
        a3 += vp[384 + i];                  // cross partials
    red1[threadIdx.x] = a1;
    red2[threadIdx.x] = a2;
    red3[threadIdx.x] = a3;
    __syncthreads();
    for (int s = 128; s > 0; s >>= 1) {
        if (threadIdx.x < s) {
            red1[threadIdx.x] += red1[threadIdx.x + s];
            red2[threadIdx.x] += red2[threadIdx.x + s];
            red3[threadIdx.x] += red3[threadIdx.x + s];
        }
        __syncthreads();
    }
    if (threadIdx.x == 0) {
        double same = (red2[0] > 0.0) ? red1[0] / red2[0] : 0.0;
        double diff = red3[0] / TOTAL_PAIRS;
        out[0] = (float)(same + diff);
    }
}

extern "C" void kernel_launch(void* const* d_in, const int* in_sizes, int n_in,
                              void* d_out, int out_size, void* d_ws, size_t ws_size,
                              hipStream_t stream) {
    const float* X = (const float*)d_in[0];   // outputs [N, D] fp32
    const float* L = (const float*)d_in[1];   // labels  [N, C] fp32
    double* dpart = (double*)d_ws;               // 896 doubles = floats [0,1792)
    float* wsf = (float*)d_ws;
    unsigned* done = (unsigned*)(wsf + 1792);
    int* lbl = (int*)(wsf + 1796);               // N ints
    float* sq = wsf + 9988;                      // N floats
    float* out = (float*)d_out;

    hipLaunchKernelGGL(k_rows, dim3(N / 4), dim3(256), 0, stream,
                       X, L, lbl, sq, done);
    hipLaunchKernelGGL(k2, dim3(NB_K2), dim3(256), 0, stream,
                       X, lbl, sq, dpart, done, out);
}